// Round 3
// baseline (653.536 us; speedup 1.0000x reference)
//
#include <hip/hip_runtime.h>

// MoE layer: B=4,T=1024,C=1024,H=4096,E=8, top-2 routing, shared expert.
// Sparse formulation: only top-2 experts per token are computed.
//
// R3: GEMM LDS layout made bank-conflict-free (source pre-swizzle, lane-major
// [16row][4kslot] chunks -> every ds_read_b128 is lane-linear; was 8-way
// conflicted, 1.3e7 conflict cycles on gemm_o). + bijective XCD swizzle on
// GEMM grids for L2 locality (FETCH 524MB @ 30% HBM util).

typedef unsigned short u16;
typedef __bf16 bf16x8 __attribute__((ext_vector_type(8)));
typedef float f32x4 __attribute__((ext_vector_type(4)));

#define NTOK 4096
#define CDIM 1024
#define HDIM 4096
#define NEXP 8
#define SLOTS 13312   // 4096 shared (identity) + 9216 routed capacity (128-aligned segs)
#define NTILES 104    // SLOTS/128
#define RBLK 1024     // router grid (4 tokens/block)

static __device__ __forceinline__ u16 f2bf(float f) {   // round-to-nearest-even
  unsigned u = __float_as_uint(f);
  u += 0x7fffu + ((u >> 16) & 1u);
  return (u16)(u >> 16);
}

static __device__ __forceinline__ void gload16(const void* g, void* l) {
  __builtin_amdgcn_global_load_lds((const __attribute__((address_space(1))) unsigned int*)g,
                                   (__attribute__((address_space(3))) unsigned int*)l,
                                   16, 0, 0);
}

// ---------------- init: zero cursor, identity/pad slot map ----------------
__global__ void init_kernel(int* order, int* tile_expert, int* cursor) {
  int i = blockIdx.x * 256 + threadIdx.x;      // grid 52*256 = 13312
  if (i < SLOTS) order[i] = (i < NTOK) ? i : -1;
  if (i < NTILES) tile_expert[i] = (i < 32) ? 8 : -1;   // tiles 0..31 = shared expert
  if (i < NEXP) cursor[i] = 0;
}

// ---------------- X fp32 -> bf16 ----------------
__global__ void xconv_kernel(const float* __restrict__ X, u16* __restrict__ Xb) {
  int i = blockIdx.x * 256 + threadIdx.x;      // 4 elems each
  float4 v = ((const float4*)X)[i];
  u16 o0 = f2bf(v.x), o1 = f2bf(v.y), o2 = f2bf(v.z), o3 = f2bf(v.w);
  unsigned long long pack = (unsigned long long)o0 | ((unsigned long long)o1 << 16)
                          | ((unsigned long long)o2 << 32) | ((unsigned long long)o3 << 48);
  ((unsigned long long*)Xb)[i] = pack;
}

// ---------------- transpose + convert: src fp32 [b][R][Cc] -> dst bf16 [b][Cc][R] ----------------
__global__ void tconv_kernel(const float* __restrict__ src, u16* __restrict__ dst, int R, int Cc) {
  __shared__ float t[32][33];
  const size_t bofs = (size_t)blockIdx.z * R * Cc;
  src += bofs; dst += bofs;
  int tx = threadIdx.x & 31, ty = threadIdx.x >> 5;   // 32x8
  int r0 = blockIdx.y * 32, c0 = blockIdx.x * 32;
#pragma unroll
  for (int i = 0; i < 32; i += 8)
    t[ty + i][tx] = src[(size_t)(r0 + ty + i) * Cc + c0 + tx];
  __syncthreads();
#pragma unroll
  for (int i = 0; i < 32; i += 8)
    dst[(size_t)(c0 + ty + i) * R + r0 + tx] = f2bf(t[tx][ty + i]);
}

// ---------------- router: 1 wave/token, block-local reduction, NO global atomics ----------------
__global__ __launch_bounds__(256) void router_kernel(
    const float* __restrict__ X, const float* __restrict__ rw,
    float* __restrict__ w01, int* __restrict__ e01,
    float* __restrict__ pP, int* __restrict__ pC) {
  __shared__ float wP[4][8];
  __shared__ int wE[4][2];
  const int tid = threadIdx.x;
  const int w = tid >> 6, l = tid & 63;
  const int wid = blockIdx.x * 4 + w;   // token
  const float* x = X + (size_t)wid * CDIM;
  float s[8] = {0.f,0.f,0.f,0.f,0.f,0.f,0.f,0.f};
#pragma unroll 4
  for (int i = 0; i < 16; ++i) {
    int c = i * 64 + l;
    float xv = x[c];
    const float4* rp = (const float4*)(rw + c * 8);
    float4 r0 = rp[0], r1 = rp[1];
    s[0] += xv * r0.x; s[1] += xv * r0.y; s[2] += xv * r0.z; s[3] += xv * r0.w;
    s[4] += xv * r1.x; s[5] += xv * r1.y; s[6] += xv * r1.z; s[7] += xv * r1.w;
  }
#pragma unroll
  for (int off = 32; off; off >>= 1)
#pragma unroll
    for (int e = 0; e < 8; ++e) s[e] += __shfl_down(s[e], off);
  if (l == 0) {
    float m = s[0];
#pragma unroll
    for (int e = 1; e < 8; ++e) m = fmaxf(m, s[e]);
    float p[8], d = 0.f;
#pragma unroll
    for (int e = 0; e < 8; ++e) { p[e] = expf(s[e] - m); d += p[e]; }
    float inv = 1.f / d;
#pragma unroll
    for (int e = 0; e < 8; ++e) p[e] *= inv;
    int e0 = 0;
#pragma unroll
    for (int e = 1; e < 8; ++e) if (p[e] > p[e0]) e0 = e;   // ties -> lowest idx (jax)
    int e1 = -1;
#pragma unroll
    for (int e = 0; e < 8; ++e) if (e != e0 && (e1 < 0 || p[e] > p[e1])) e1 = e;
    w01[wid * 2] = p[e0]; w01[wid * 2 + 1] = p[e1];
    e01[wid * 2] = e0;    e01[wid * 2 + 1] = e1;
#pragma unroll
    for (int e = 0; e < 8; ++e) wP[w][e] = p[e];
    wE[w][0] = e0; wE[w][1] = e1;
  }
  __syncthreads();
  if (tid < 8) {
    pP[blockIdx.x * 8 + tid] = wP[0][tid] + wP[1][tid] + wP[2][tid] + wP[3][tid];
    int c = 0;
#pragma unroll
    for (int v = 0; v < 4; ++v) c += (wE[v][0] == tid) + (wE[v][1] == tid);
    pC[blockIdx.x * 8 + tid] = c;
  }
}

// ---------------- setup: reduce partials, offsets, tile map, aux loss ----------------
__global__ __launch_bounds__(256) void setup_kernel(
    const float* __restrict__ pP, const int* __restrict__ pC,
    int* __restrict__ roff, int* __restrict__ tile_expert, float* __restrict__ out_aux) {
  __shared__ float sP[32][8];
  __shared__ int   sC[32][8];
  const int tid = threadIdx.x;
  const int e = tid & 7, g = tid >> 3;   // 32 groups x 8 experts
  float fs = 0.f; int cs = 0;
  for (int b = g; b < RBLK; b += 32) { fs += pP[b * 8 + e]; cs += pC[b * 8 + e]; }
  sP[g][e] = fs; sC[g][e] = cs;
  __syncthreads();
  if (tid == 0) {
    float P[8]; int C[8];
    for (int e2 = 0; e2 < 8; ++e2) {
      float f2 = 0.f; int c2 = 0;
      for (int g2 = 0; g2 < 32; ++g2) { f2 += sP[g2][e2]; c2 += sC[g2][e2]; }
      P[e2] = f2; C[e2] = c2;
    }
    int off = NTOK;
    float a = 0.f;
    for (int e2 = 0; e2 < NEXP; ++e2) {
      roff[e2] = off;
      int nt = (C[e2] + 127) >> 7;
      int t0 = off >> 7;
      for (int i = 0; i < nt; ++i) tile_expert[t0 + i] = e2;
      off += nt << 7;
      a += (C[e2] * (1.f / NTOK)) * (P[e2] * (1.f / NTOK));
    }
    out_aux[0] = (float)NEXP * a;
  }
}

// ---------------- scatter: token -> slots, block-aggregated cursor ----------------
__global__ __launch_bounds__(256) void scatter_kernel(
    const int* __restrict__ e01, const int* __restrict__ roff,
    int* __restrict__ cursor, int* __restrict__ order, int* __restrict__ slot_of) {
  __shared__ int cnt_l[8];
  __shared__ int base_l[8];
  const int tid = threadIdx.x;
  const int t = blockIdx.x * 256 + tid;   // grid 16 blocks
  if (tid < 8) cnt_l[tid] = 0;
  __syncthreads();
  int e0 = e01[t * 2], e1 = e01[t * 2 + 1];
  int p0 = atomicAdd(&cnt_l[e0], 1);      // LDS atomics
  int p1 = atomicAdd(&cnt_l[e1], 1);
  __syncthreads();
  if (tid < 8) base_l[tid] = atomicAdd(&cursor[tid], cnt_l[tid]);  // 8 global atomics/block
  __syncthreads();
  int s0 = roff[e0] + base_l[e0] + p0;
  int s1 = roff[e1] + base_l[e1] + p1;
  order[s0] = t; order[s1] = t;
  slot_of[t * 2] = s0; slot_of[t * 2 + 1] = s1;
}

// LDS layout (both GEMMs): per 64-row staging round, 4 wave-chunks of
// [16 rows][4 kslots] stored lane-major: chunk g (rows 16g..16g+15), slot l
// holds (row = 16g + (l&15), k = (l>>4)*8 .. +7). Fragment read for row-group
// g at lane l is &buf[g*512 + l*8] -> byte addr = lane*16, conflict-free.

// ---------------- GEMM1: hidden = relu(A @ W1^T + b1), A rows via order[], out bf16 ----------------
__global__ __launch_bounds__(256) void gemm_h_kernel(
    const u16* __restrict__ Xb, const u16* __restrict__ W1t, const u16* __restrict__ RW1t,
    const float* __restrict__ sh_b1, const float* __restrict__ rt_b1,
    const int* __restrict__ tile_expert, const int* __restrict__ order,
    u16* __restrict__ Hu) {
  // bijective XCD swizzle: nwg = 32*104 = 3328, q = 416 (n-fast decode)
  const int orig = blockIdx.y * 32 + blockIdx.x;
  const int wg = (orig & 7) * 416 + (orig >> 3);
  const int tile = wg >> 5, nidx = wg & 31;
  int e = tile_expert[tile];
  if (e < 0) return;
  const u16* Bw = (e == 8) ? W1t : RW1t + (size_t)e * HDIM * CDIM;
  const float* bias = (e == 8) ? sh_b1 : rt_b1 + e * HDIM;

  __shared__ u16 As[128 * 32];
  __shared__ u16 Bs[128 * 32];

  const int tid = threadIdx.x;
  const int l = tid & 63, w = tid >> 6;
  const int wm = w >> 1, wn = w & 1;
  const int fr = l & 15, fq = l >> 4;
  const int m0 = tile * 128, n0 = nidx * 128;
  const int sr = (w << 4) + (tid & 15);     // staging row within 64-row round (lane-major chunks)
  const int sk = ((tid >> 4) & 3) * 8;      // staging k offset (elems)
  const int l8 = l * 8;                     // fragment read offset (elems)

  int tok0 = order[m0 + sr];      if (tok0 < 0) tok0 = 0;
  int tok1 = order[m0 + 64 + sr]; if (tok1 < 0) tok1 = 0;
  const u16* aS0 = Xb + (size_t)tok0 * CDIM + sk;
  const u16* aS1 = Xb + (size_t)tok1 * CDIM + sk;
  const u16* bS0 = Bw + (size_t)(n0 + sr) * CDIM + sk;
  const u16* bS1 = Bw + (size_t)(n0 + 64 + sr) * CDIM + sk;
  u16* aD0 = As + w * 512;  u16* aD1 = As + 2048 + w * 512;   // wave-uniform LDS bases
  u16* bD0 = Bs + w * 512;  u16* bD1 = Bs + 2048 + w * 512;

  f32x4 acc[4][4] = {};
  for (int kt = 0; kt < CDIM / 32; ++kt) {
    gload16(aS0, aD0); gload16(aS1, aD1);
    gload16(bS0, bD0); gload16(bS1, bD1);
    aS0 += 32; aS1 += 32; bS0 += 32; bS1 += 32;
    __syncthreads();
    bf16x8 af[4], bv[4];
#pragma unroll
    for (int i = 0; i < 4; ++i) af[i] = *(const bf16x8*)&As[(wm * 4 + i) * 512 + l8];
#pragma unroll
    for (int j = 0; j < 4; ++j) bv[j] = *(const bf16x8*)&Bs[(wn * 4 + j) * 512 + l8];
#pragma unroll
    for (int i = 0; i < 4; ++i)
#pragma unroll
      for (int j = 0; j < 4; ++j)
        acc[i][j] = __builtin_amdgcn_mfma_f32_16x16x32_bf16(af[i], bv[j], acc[i][j], 0, 0, 0);
    __syncthreads();
  }

  const size_t mb = m0 + wm * 64;
  const int nb = n0 + wn * 64;
#pragma unroll
  for (int j = 0; j < 4; ++j) {
    const int n_g = nb + j * 16 + fr;
    const float bvf = bias[n_g];
#pragma unroll
    for (int i = 0; i < 4; ++i)
#pragma unroll
      for (int r = 0; r < 4; ++r) {
        float v = acc[i][j][r] + bvf;
        v = fmaxf(v, 0.0f);
        Hu[(mb + i * 16 + fq * 4 + r) * (size_t)HDIM + n_g] = f2bf(v);
      }
  }
}

// ---------------- GEMM2: Yu = Hu @ W2^T + b2 (fp32 out) ----------------
__global__ __launch_bounds__(256) void gemm_o_kernel(
    const u16* __restrict__ Hu, const u16* __restrict__ W2t, const u16* __restrict__ RW2t,
    const float* __restrict__ sh_b2, const float* __restrict__ rt_b2,
    const int* __restrict__ tile_expert,
    float* __restrict__ Yu) {
  // bijective XCD swizzle: nwg = 8*104 = 832, q = 104 (n-fast decode)
  const int orig = blockIdx.y * 8 + blockIdx.x;
  const int wg = (orig & 7) * 104 + (orig >> 3);
  const int tile = wg >> 3, nidx = wg & 7;
  int e = tile_expert[tile];
  if (e < 0) return;
  const u16* Bw = (e == 8) ? W2t : RW2t + (size_t)e * CDIM * HDIM;
  const float* bias = (e == 8) ? sh_b2 : rt_b2 + e * CDIM;

  __shared__ u16 As[128 * 32];
  __shared__ u16 Bs[128 * 32];

  const int tid = threadIdx.x;
  const int l = tid & 63, w = tid >> 6;
  const int wm = w >> 1, wn = w & 1;
  const int fr = l & 15, fq = l >> 4;
  const int m0 = tile * 128, n0 = nidx * 128;
  const int sr = (w << 4) + (tid & 15);
  const int sk = ((tid >> 4) & 3) * 8;
  const int l8 = l * 8;

  const u16* aS0 = Hu + (size_t)(m0 + sr) * HDIM + sk;
  const u16* aS1 = Hu + (size_t)(m0 + 64 + sr) * HDIM + sk;
  const u16* bS0 = Bw + (size_t)(n0 + sr) * HDIM + sk;
  const u16* bS1 = Bw + (size_t)(n0 + 64 + sr) * HDIM + sk;
  u16* aD0 = As + w * 512;  u16* aD1 = As + 2048 + w * 512;
  u16* bD0 = Bs + w * 512;  u16* bD1 = Bs + 2048 + w * 512;

  f32x4 acc[4][4] = {};
  for (int kt = 0; kt < HDIM / 32; ++kt) {
    gload16(aS0, aD0); gload16(aS1, aD1);
    gload16(bS0, bD0); gload16(bS1, bD1);
    aS0 += 32; aS1 += 32; bS0 += 32; bS1 += 32;
    __syncthreads();
    bf16x8 af[4], bv[4];
#pragma unroll
    for (int i = 0; i < 4; ++i) af[i] = *(const bf16x8*)&As[(wm * 4 + i) * 512 + l8];
#pragma unroll
    for (int j = 0; j < 4; ++j) bv[j] = *(const bf16x8*)&Bs[(wn * 4 + j) * 512 + l8];
#pragma unroll
    for (int i = 0; i < 4; ++i)
#pragma unroll
      for (int j = 0; j < 4; ++j)
        acc[i][j] = __builtin_amdgcn_mfma_f32_16x16x32_bf16(af[i], bv[j], acc[i][j], 0, 0, 0);
    __syncthreads();
  }

  const size_t mb = m0 + wm * 64;
  const int nb = n0 + wn * 64;
#pragma unroll
  for (int j = 0; j < 4; ++j) {
    const int n_g = nb + j * 16 + fr;
    const float bvf = bias[n_g];
#pragma unroll
    for (int i = 0; i < 4; ++i)
#pragma unroll
      for (int r = 0; r < 4; ++r)
        Yu[(mb + i * 16 + fq * 4 + r) * (size_t)CDIM + n_g] = acc[i][j][r] + bvf;
  }
}

// ---------------- combine: out = shared + w0*expert0 + w1*expert1 ----------------
__global__ void combine_kernel(const float* __restrict__ Yu, const float* __restrict__ w01,
                               const int* __restrict__ slot_of, float* __restrict__ out) {
  int gid = blockIdx.x * 256 + threadIdx.x;   // 4096 blocks; 256 float4 per token row
  int t = gid >> 8;
  int c4 = gid & 255;
  int s0 = slot_of[t * 2], s1 = slot_of[t * 2 + 1];
  float wq0 = w01[t * 2], wq1 = w01[t * 2 + 1];
  float4 a  = ((const float4*)(Yu + (size_t)t  * CDIM))[c4];
  float4 b0 = ((const float4*)(Yu + (size_t)s0 * CDIM))[c4];
  float4 b1 = ((const float4*)(Yu + (size_t)s1 * CDIM))[c4];
  float4 rv;
  rv.x = a.x + wq0 * b0.x + wq1 * b1.x;
  rv.y = a.y + wq0 * b0.y + wq1 * b1.y;
  rv.z = a.z + wq0 * b0.z + wq1 * b1.z;
  rv.w = a.w + wq0 * b0.w + wq1 * b1.w;
  ((float4*)out)[gid] = rv;
}

extern "C" void kernel_launch(void* const* d_in, const int* in_sizes, int n_in,
                              void* d_out, int out_size, void* d_ws, size_t ws_size,
                              hipStream_t stream) {
  const float* X        = (const float*)d_in[0];   // [4096,1024]
  const float* router_w = (const float*)d_in[1];   // [1024,8]
  const float* sh_w1    = (const float*)d_in[2];   // [1024,4096]
  const float* sh_b1    = (const float*)d_in[3];   // [4096]
  const float* sh_w2    = (const float*)d_in[4];   // [4096,1024]
  const float* sh_b2    = (const float*)d_in[5];   // [1024]
  const float* rt_w1    = (const float*)d_in[6];   // [8,1024,4096]
  const float* rt_b1    = (const float*)d_in[7];   // [8,4096]
  const float* rt_w2    = (const float*)d_in[8];   // [8,4096,1024]
  const float* rt_b2    = (const float*)d_in[9];   // [8,1024]
  float* out = (float*)d_out;

  // ---- workspace layout ----
  char* p = (char*)d_ws;
  auto take = [&](size_t bytes) { char* q = p; p += (bytes + 255) & ~(size_t)255; return q; };
  u16*  Xb   = (u16*)take((size_t)NTOK * CDIM * 2);        //   8 MB
  u16*  W1t  = (u16*)take((size_t)HDIM * CDIM * 2);        //   8 MB  sh_w1^T [H][C]
  u16*  W2t  = (u16*)take((size_t)CDIM * HDIM * 2);        //   8 MB  sh_w2^T [C][H]
  u16*  RW1t = (u16*)take((size_t)NEXP * HDIM * CDIM * 2); //  64 MB  [E][H][C]
  u16*  RW2t = (u16*)take((size_t)NEXP * CDIM * HDIM * 2); //  64 MB  [E][C][H]
  u16*  Hu   = (u16*)take((size_t)SLOTS * HDIM * 2);       // 104 MB
  float* Yu  = (float*)take((size_t)SLOTS * CDIM * 4);     //  52 MB
  float* w01 = (float*)take((size_t)NTOK * 2 * 4);
  int*  e01  = (int*)take((size_t)NTOK * 2 * 4);
  int*  slot_of = (int*)take((size_t)NTOK * 2 * 4);
  int*  order   = (int*)take((size_t)SLOTS * 4);
  int*  tile_expert = (int*)take((size_t)NTILES * 4);
  float* pP  = (float*)take((size_t)RBLK * 8 * 4);         //  32 KB router prob partials
  int*  pC   = (int*)take((size_t)RBLK * 8 * 4);           //  32 KB router count partials
  int*  cursor = (int*)take(256);
  int*  roff   = (int*)take(256);
  size_t need = (size_t)(p - (char*)d_ws);
  if (ws_size < need) return;  // insufficient scratch -> fail visibly (poisoned out)

  // ---- pipeline ----
  init_kernel<<<52, 256, 0, stream>>>(order, tile_expert, cursor);
  xconv_kernel<<<(NTOK * CDIM / 4) / 256, 256, 0, stream>>>(X, Xb);
  tconv_kernel<<<dim3(HDIM / 32, CDIM / 32, 1), 256, 0, stream>>>(sh_w1, W1t, CDIM, HDIM);
  tconv_kernel<<<dim3(CDIM / 32, HDIM / 32, 1), 256, 0, stream>>>(sh_w2, W2t, HDIM, CDIM);
  tconv_kernel<<<dim3(HDIM / 32, CDIM / 32, NEXP), 256, 0, stream>>>(rt_w1, RW1t, CDIM, HDIM);
  tconv_kernel<<<dim3(CDIM / 32, HDIM / 32, NEXP), 256, 0, stream>>>(rt_w2, RW2t, HDIM, CDIM);
  router_kernel<<<RBLK, 256, 0, stream>>>(X, router_w, w01, e01, pP, pC);
  setup_kernel<<<1, 256, 0, stream>>>(pP, pC, roff, tile_expert, out + (size_t)NTOK * CDIM);
  scatter_kernel<<<NTOK / 256, 256, 0, stream>>>(e01, roff, cursor, order, slot_of);
  gemm_h_kernel<<<dim3(32, NTILES), 256, 0, stream>>>(
      Xb, W1t, RW1t, sh_b1, rt_b1, tile_expert, order, Hu);
  gemm_o_kernel<<<dim3(8, NTILES), 256, 0, stream>>>(
      Hu, W2t, RW2t, sh_b2, rt_b2, tile_expert, Yu);
  combine_kernel<<<(NTOK * CDIM / 4) / 256, 256, 0, stream>>>(Yu, w01, slot_of, out);
}

// Round 4
// 618.857 us; speedup vs baseline: 1.0560x; 1.0560x over previous
//
#include <hip/hip_runtime.h>

// MoE layer: B=4,T=1024,C=1024,H=4096,E=8, top-2 routing, shared expert.
// Sparse formulation: only top-2 experts per token are computed.
//
// R4: GEMMs restructured to T3 "minimum 2-phase": BK=64, double-buffered LDS,
// ONE barrier per K-step (was 2 per 32-K -> stall-bound: MfmaUtil 15%,
// VALUBusy 6%, HBM 9% -- all pipes idle). Stage(next) issued before
// ds_read+MFMA(cur); setprio(1) around MFMA cluster (T5). Lane-major
// conflict-free LDS chunks kept (R3: conflicts == 0).

typedef unsigned short u16;
typedef __bf16 bf16x8 __attribute__((ext_vector_type(8)));
typedef float f32x4 __attribute__((ext_vector_type(4)));

#define NTOK 4096
#define CDIM 1024
#define HDIM 4096
#define NEXP 8
#define SLOTS 13312   // 4096 shared (identity) + 9216 routed capacity (128-aligned segs)
#define NTILES 104    // SLOTS/128
#define RBLK 1024     // router grid (4 tokens/block)

static __device__ __forceinline__ u16 f2bf(float f) {   // round-to-nearest-even
  unsigned u = __float_as_uint(f);
  u += 0x7fffu + ((u >> 16) & 1u);
  return (u16)(u >> 16);
}

static __device__ __forceinline__ void gload16(const void* g, void* l) {
  __builtin_amdgcn_global_load_lds((const __attribute__((address_space(1))) unsigned int*)g,
                                   (__attribute__((address_space(3))) unsigned int*)l,
                                   16, 0, 0);
}

// ---------------- init: zero cursor, identity/pad slot map ----------------
__global__ void init_kernel(int* order, int* tile_expert, int* cursor) {
  int i = blockIdx.x * 256 + threadIdx.x;      // grid 52*256 = 13312
  if (i < SLOTS) order[i] = (i < NTOK) ? i : -1;
  if (i < NTILES) tile_expert[i] = (i < 32) ? 8 : -1;   // tiles 0..31 = shared expert
  if (i < NEXP) cursor[i] = 0;
}

// ---------------- X fp32 -> bf16 ----------------
__global__ void xconv_kernel(const float* __restrict__ X, u16* __restrict__ Xb) {
  int i = blockIdx.x * 256 + threadIdx.x;      // 4 elems each
  float4 v = ((const float4*)X)[i];
  u16 o0 = f2bf(v.x), o1 = f2bf(v.y), o2 = f2bf(v.z), o3 = f2bf(v.w);
  unsigned long long pack = (unsigned long long)o0 | ((unsigned long long)o1 << 16)
                          | ((unsigned long long)o2 << 32) | ((unsigned long long)o3 << 48);
  ((unsigned long long*)Xb)[i] = pack;
}

// ---------------- transpose + convert: src fp32 [b][R][Cc] -> dst bf16 [b][Cc][R] ----------------
__global__ void tconv_kernel(const float* __restrict__ src, u16* __restrict__ dst, int R, int Cc) {
  __shared__ float t[32][33];
  const size_t bofs = (size_t)blockIdx.z * R * Cc;
  src += bofs; dst += bofs;
  int tx = threadIdx.x & 31, ty = threadIdx.x >> 5;   // 32x8
  int r0 = blockIdx.y * 32, c0 = blockIdx.x * 32;
#pragma unroll
  for (int i = 0; i < 32; i += 8)
    t[ty + i][tx] = src[(size_t)(r0 + ty + i) * Cc + c0 + tx];
  __syncthreads();
#pragma unroll
  for (int i = 0; i < 32; i += 8)
    dst[(size_t)(c0 + ty + i) * R + r0 + tx] = f2bf(t[tx][ty + i]);
}

// ---------------- router: 1 wave/token, block-local reduction, NO global atomics ----------------
__global__ __launch_bounds__(256) void router_kernel(
    const float* __restrict__ X, const float* __restrict__ rw,
    float* __restrict__ w01, int* __restrict__ e01,
    float* __restrict__ pP, int* __restrict__ pC) {
  __shared__ float wP[4][8];
  __shared__ int wE[4][2];
  const int tid = threadIdx.x;
  const int w = tid >> 6, l = tid & 63;
  const int wid = blockIdx.x * 4 + w;   // token
  const float* x = X + (size_t)wid * CDIM;
  float s[8] = {0.f,0.f,0.f,0.f,0.f,0.f,0.f,0.f};
#pragma unroll 4
  for (int i = 0; i < 16; ++i) {
    int c = i * 64 + l;
    float xv = x[c];
    const float4* rp = (const float4*)(rw + c * 8);
    float4 r0 = rp[0], r1 = rp[1];
    s[0] += xv * r0.x; s[1] += xv * r0.y; s[2] += xv * r0.z; s[3] += xv * r0.w;
    s[4] += xv * r1.x; s[5] += xv * r1.y; s[6] += xv * r1.z; s[7] += xv * r1.w;
  }
#pragma unroll
  for (int off = 32; off; off >>= 1)
#pragma unroll
    for (int e = 0; e < 8; ++e) s[e] += __shfl_down(s[e], off);
  if (l == 0) {
    float m = s[0];
#pragma unroll
    for (int e = 1; e < 8; ++e) m = fmaxf(m, s[e]);
    float p[8], d = 0.f;
#pragma unroll
    for (int e = 0; e < 8; ++e) { p[e] = expf(s[e] - m); d += p[e]; }
    float inv = 1.f / d;
#pragma unroll
    for (int e = 0; e < 8; ++e) p[e] *= inv;
    int e0 = 0;
#pragma unroll
    for (int e = 1; e < 8; ++e) if (p[e] > p[e0]) e0 = e;   // ties -> lowest idx (jax)
    int e1 = -1;
#pragma unroll
    for (int e = 0; e < 8; ++e) if (e != e0 && (e1 < 0 || p[e] > p[e1])) e1 = e;
    w01[wid * 2] = p[e0]; w01[wid * 2 + 1] = p[e1];
    e01[wid * 2] = e0;    e01[wid * 2 + 1] = e1;
#pragma unroll
    for (int e = 0; e < 8; ++e) wP[w][e] = p[e];
    wE[w][0] = e0; wE[w][1] = e1;
  }
  __syncthreads();
  if (tid < 8) {
    pP[blockIdx.x * 8 + tid] = wP[0][tid] + wP[1][tid] + wP[2][tid] + wP[3][tid];
    int c = 0;
#pragma unroll
    for (int v = 0; v < 4; ++v) c += (wE[v][0] == tid) + (wE[v][1] == tid);
    pC[blockIdx.x * 8 + tid] = c;
  }
}

// ---------------- setup: reduce partials, offsets, tile map, aux loss ----------------
__global__ __launch_bounds__(256) void setup_kernel(
    const float* __restrict__ pP, const int* __restrict__ pC,
    int* __restrict__ roff, int* __restrict__ tile_expert, float* __restrict__ out_aux) {
  __shared__ float sP[32][8];
  __shared__ int   sC[32][8];
  const int tid = threadIdx.x;
  const int e = tid & 7, g = tid >> 3;   // 32 groups x 8 experts
  float fs = 0.f; int cs = 0;
  for (int b = g; b < RBLK; b += 32) { fs += pP[b * 8 + e]; cs += pC[b * 8 + e]; }
  sP[g][e] = fs; sC[g][e] = cs;
  __syncthreads();
  if (tid == 0) {
    float P[8]; int C[8];
    for (int e2 = 0; e2 < 8; ++e2) {
      float f2 = 0.f; int c2 = 0;
      for (int g2 = 0; g2 < 32; ++g2) { f2 += sP[g2][e2]; c2 += sC[g2][e2]; }
      P[e2] = f2; C[e2] = c2;
    }
    int off = NTOK;
    float a = 0.f;
    for (int e2 = 0; e2 < NEXP; ++e2) {
      roff[e2] = off;
      int nt = (C[e2] + 127) >> 7;
      int t0 = off >> 7;
      for (int i = 0; i < nt; ++i) tile_expert[t0 + i] = e2;
      off += nt << 7;
      a += (C[e2] * (1.f / NTOK)) * (P[e2] * (1.f / NTOK));
    }
    out_aux[0] = (float)NEXP * a;
  }
}

// ---------------- scatter: token -> slots, block-aggregated cursor ----------------
__global__ __launch_bounds__(256) void scatter_kernel(
    const int* __restrict__ e01, const int* __restrict__ roff,
    int* __restrict__ cursor, int* __restrict__ order, int* __restrict__ slot_of) {
  __shared__ int cnt_l[8];
  __shared__ int base_l[8];
  const int tid = threadIdx.x;
  const int t = blockIdx.x * 256 + tid;   // grid 16 blocks
  if (tid < 8) cnt_l[tid] = 0;
  __syncthreads();
  int e0 = e01[t * 2], e1 = e01[t * 2 + 1];
  int p0 = atomicAdd(&cnt_l[e0], 1);      // LDS atomics
  int p1 = atomicAdd(&cnt_l[e1], 1);
  __syncthreads();
  if (tid < 8) base_l[tid] = atomicAdd(&cursor[tid], cnt_l[tid]);  // 8 global atomics/block
  __syncthreads();
  int s0 = roff[e0] + base_l[e0] + p0;
  int s1 = roff[e1] + base_l[e1] + p1;
  order[s0] = t; order[s1] = t;
  slot_of[t * 2] = s0; slot_of[t * 2 + 1] = s1;
}

// LDS layout (both GEMMs): per 128x64 tile, 16 chunks of 1KB. Chunk c = g*2+kk
// (g = 16-row group, kk = 32-wide k-half); slot l holds (row = g*16 + (l&15),
// k = kk*32 + (l>>4)*8 .. +7). Every ds_read_b128 and every gload16 dest is
// wave-uniform base + lane*16B -> zero bank conflicts (verified R3).

// ---------------- GEMM1: hidden = relu(A @ W1^T + b1), A rows via order[], out bf16 ----------------
__global__ __launch_bounds__(256) void gemm_h_kernel(
    const u16* __restrict__ Xb, const u16* __restrict__ W1t, const u16* __restrict__ RW1t,
    const float* __restrict__ sh_b1, const float* __restrict__ rt_b1,
    const int* __restrict__ tile_expert, const int* __restrict__ order,
    u16* __restrict__ Hu) {
  // bijective XCD swizzle: nwg = 32*104 = 3328, q = 416 (n-fast decode)
  const int orig = blockIdx.y * 32 + blockIdx.x;
  const int wg = (orig & 7) * 416 + (orig >> 3);
  const int tile = wg >> 5, nidx = wg & 31;
  int e = tile_expert[tile];
  if (e < 0) return;
  const u16* Bw = (e == 8) ? W1t : RW1t + (size_t)e * HDIM * CDIM;
  const float* bias = (e == 8) ? sh_b1 : rt_b1 + e * HDIM;

  __shared__ u16 As[2 * 128 * 64];   // [buf][16 chunks][512]  32KB
  __shared__ u16 Bs[2 * 128 * 64];

  const int tid = threadIdx.x;
  const int l = tid & 63, w = tid >> 6;
  const int wm = w >> 1, wn = w & 1;
  const int fr = l & 15, fq = l >> 4;
  const int m0 = tile * 128, n0 = nidx * 128;

  const int srow0 = (2 * w + 0) * 16 + fr;   // staged rows (wave w -> chunks 4w..4w+3)
  const int srow1 = (2 * w + 1) * 16 + fr;
  const int skoff = fq * 8;                  // k offset within 32-half

  int tok0 = order[m0 + srow0]; if (tok0 < 0) tok0 = 0;
  int tok1 = order[m0 + srow1]; if (tok1 < 0) tok1 = 0;
  const u16* aSrc0 = Xb + (size_t)tok0 * CDIM + skoff;
  const u16* aSrc1 = Xb + (size_t)tok1 * CDIM + skoff;
  const u16* bSrc0 = Bw + (size_t)(n0 + srow0) * CDIM + skoff;
  const u16* bSrc1 = Bw + (size_t)(n0 + srow1) * CDIM + skoff;

  auto STAGE = [&](int bufofs, int kofs) {
    gload16(aSrc0 + kofs,      As + bufofs + (4 * w + 0) * 512);
    gload16(aSrc0 + kofs + 32, As + bufofs + (4 * w + 1) * 512);
    gload16(aSrc1 + kofs,      As + bufofs + (4 * w + 2) * 512);
    gload16(aSrc1 + kofs + 32, As + bufofs + (4 * w + 3) * 512);
    gload16(bSrc0 + kofs,      Bs + bufofs + (4 * w + 0) * 512);
    gload16(bSrc0 + kofs + 32, Bs + bufofs + (4 * w + 1) * 512);
    gload16(bSrc1 + kofs,      Bs + bufofs + (4 * w + 2) * 512);
    gload16(bSrc1 + kofs + 32, Bs + bufofs + (4 * w + 3) * 512);
  };

  f32x4 acc[4][4] = {};
  const int NT = CDIM / 64;   // 16
  STAGE(0, 0);
  __syncthreads();
  int cur = 0;
  for (int t = 0; t < NT; ++t) {
    if (t + 1 < NT) STAGE((cur ^ 1) * 8192, (t + 1) * 64);
    const u16* ab = As + cur * 8192 + l * 8;
    const u16* bb = Bs + cur * 8192 + l * 8;
    bf16x8 af[4][2], bv[4][2];
#pragma unroll
    for (int i = 0; i < 4; ++i)
#pragma unroll
      for (int kk = 0; kk < 2; ++kk) {
        af[i][kk] = *(const bf16x8*)&ab[((wm * 4 + i) * 2 + kk) * 512];
        bv[i][kk] = *(const bf16x8*)&bb[((wn * 4 + i) * 2 + kk) * 512];
      }
    __builtin_amdgcn_s_setprio(1);
#pragma unroll
    for (int i = 0; i < 4; ++i)
#pragma unroll
      for (int j = 0; j < 4; ++j) {
        acc[i][j] = __builtin_amdgcn_mfma_f32_16x16x32_bf16(af[i][0], bv[j][0], acc[i][j], 0, 0, 0);
        acc[i][j] = __builtin_amdgcn_mfma_f32_16x16x32_bf16(af[i][1], bv[j][1], acc[i][j], 0, 0, 0);
      }
    __builtin_amdgcn_s_setprio(0);
    __syncthreads();
    cur ^= 1;
  }

  const size_t mb = m0 + wm * 64;
  const int nb = n0 + wn * 64;
#pragma unroll
  for (int j = 0; j < 4; ++j) {
    const int n_g = nb + j * 16 + fr;
    const float bvf = bias[n_g];
#pragma unroll
    for (int i = 0; i < 4; ++i)
#pragma unroll
      for (int r = 0; r < 4; ++r) {
        float v = acc[i][j][r] + bvf;
        v = fmaxf(v, 0.0f);
        Hu[(mb + i * 16 + fq * 4 + r) * (size_t)HDIM + n_g] = f2bf(v);
      }
  }
}

// ---------------- GEMM2: Yu = Hu @ W2^T + b2 (fp32 out) ----------------
__global__ __launch_bounds__(256) void gemm_o_kernel(
    const u16* __restrict__ Hu, const u16* __restrict__ W2t, const u16* __restrict__ RW2t,
    const float* __restrict__ sh_b2, const float* __restrict__ rt_b2,
    const int* __restrict__ tile_expert,
    float* __restrict__ Yu) {
  // bijective XCD swizzle: nwg = 8*104 = 832, q = 104 (n-fast decode)
  const int orig = blockIdx.y * 8 + blockIdx.x;
  const int wg = (orig & 7) * 104 + (orig >> 3);
  const int tile = wg >> 3, nidx = wg & 7;
  int e = tile_expert[tile];
  if (e < 0) return;
  const u16* Bw = (e == 8) ? W2t : RW2t + (size_t)e * CDIM * HDIM;
  const float* bias = (e == 8) ? sh_b2 : rt_b2 + e * CDIM;

  __shared__ u16 As[2 * 128 * 64];
  __shared__ u16 Bs[2 * 128 * 64];

  const int tid = threadIdx.x;
  const int l = tid & 63, w = tid >> 6;
  const int wm = w >> 1, wn = w & 1;
  const int fr = l & 15, fq = l >> 4;
  const int m0 = tile * 128, n0 = nidx * 128;

  const int srow0 = (2 * w + 0) * 16 + fr;
  const int srow1 = (2 * w + 1) * 16 + fr;
  const int skoff = fq * 8;

  const u16* aSrc0 = Hu + (size_t)(m0 + srow0) * HDIM + skoff;
  const u16* aSrc1 = Hu + (size_t)(m0 + srow1) * HDIM + skoff;
  const u16* bSrc0 = Bw + (size_t)(n0 + srow0) * HDIM + skoff;
  const u16* bSrc1 = Bw + (size_t)(n0 + srow1) * HDIM + skoff;

  auto STAGE = [&](int bufofs, int kofs) {
    gload16(aSrc0 + kofs,      As + bufofs + (4 * w + 0) * 512);
    gload16(aSrc0 + kofs + 32, As + bufofs + (4 * w + 1) * 512);
    gload16(aSrc1 + kofs,      As + bufofs + (4 * w + 2) * 512);
    gload16(aSrc1 + kofs + 32, As + bufofs + (4 * w + 3) * 512);
    gload16(bSrc0 + kofs,      Bs + bufofs + (4 * w + 0) * 512);
    gload16(bSrc0 + kofs + 32, Bs + bufofs + (4 * w + 1) * 512);
    gload16(bSrc1 + kofs,      Bs + bufofs + (4 * w + 2) * 512);
    gload16(bSrc1 + kofs + 32, Bs + bufofs + (4 * w + 3) * 512);
  };

  f32x4 acc[4][4] = {};
  const int NT = HDIM / 64;   // 64
  STAGE(0, 0);
  __syncthreads();
  int cur = 0;
  for (int t = 0; t < NT; ++t) {
    if (t + 1 < NT) STAGE((cur ^ 1) * 8192, (t + 1) * 64);
    const u16* ab = As + cur * 8192 + l * 8;
    const u16* bb = Bs + cur * 8192 + l * 8;
    bf16x8 af[4][2], bv[4][2];
#pragma unroll
    for (int i = 0; i < 4; ++i)
#pragma unroll
      for (int kk = 0; kk < 2; ++kk) {
        af[i][kk] = *(const bf16x8*)&ab[((wm * 4 + i) * 2 + kk) * 512];
        bv[i][kk] = *(const bf16x8*)&bb[((wn * 4 + i) * 2 + kk) * 512];
      }
    __builtin_amdgcn_s_setprio(1);
#pragma unroll
    for (int i = 0; i < 4; ++i)
#pragma unroll
      for (int j = 0; j < 4; ++j) {
        acc[i][j] = __builtin_amdgcn_mfma_f32_16x16x32_bf16(af[i][0], bv[j][0], acc[i][j], 0, 0, 0);
        acc[i][j] = __builtin_amdgcn_mfma_f32_16x16x32_bf16(af[i][1], bv[j][1], acc[i][j], 0, 0, 0);
      }
    __builtin_amdgcn_s_setprio(0);
    __syncthreads();
    cur ^= 1;
  }

  const size_t mb = m0 + wm * 64;
  const int nb = n0 + wn * 64;
#pragma unroll
  for (int j = 0; j < 4; ++j) {
    const int n_g = nb + j * 16 + fr;
    const float bvf = bias[n_g];
#pragma unroll
    for (int i = 0; i < 4; ++i)
#pragma unroll
      for (int r = 0; r < 4; ++r)
        Yu[(mb + i * 16 + fq * 4 + r) * (size_t)CDIM + n_g] = acc[i][j][r] + bvf;
  }
}

// ---------------- combine: out = shared + w0*expert0 + w1*expert1 ----------------
__global__ void combine_kernel(const float* __restrict__ Yu, const float* __restrict__ w01,
                               const int* __restrict__ slot_of, float* __restrict__ out) {
  int gid = blockIdx.x * 256 + threadIdx.x;   // 4096 blocks; 256 float4 per token row
  int t = gid >> 8;
  int c4 = gid & 255;
  int s0 = slot_of[t * 2], s1 = slot_of[t * 2 + 1];
  float wq0 = w01[t * 2], wq1 = w01[t * 2 + 1];
  float4 a  = ((const float4*)(Yu + (size_t)t  * CDIM))[c4];
  float4 b0 = ((const float4*)(Yu + (size_t)s0 * CDIM))[c4];
  float4 b1 = ((const float4*)(Yu + (size_t)s1 * CDIM))[c4];
  float4 rv;
  rv.x = a.x + wq0 * b0.x + wq1 * b1.x;
  rv.y = a.y + wq0 * b0.y + wq1 * b1.y;
  rv.z = a.z + wq0 * b0.z + wq1 * b1.z;
  rv.w = a.w + wq0 * b0.w + wq1 * b1.w;
  ((float4*)out)[gid] = rv;
}

extern "C" void kernel_launch(void* const* d_in, const int* in_sizes, int n_in,
                              void* d_out, int out_size, void* d_ws, size_t ws_size,
                              hipStream_t stream) {
  const float* X        = (const float*)d_in[0];   // [4096,1024]
  const float* router_w = (const float*)d_in[1];   // [1024,8]
  const float* sh_w1    = (const float*)d_in[2];   // [1024,4096]
  const float* sh_b1    = (const float*)d_in[3];   // [4096]
  const float* sh_w2    = (const float*)d_in[4];   // [4096,1024]
  const float* sh_b2    = (const float*)d_in[5];   // [1024]
  const float* rt_w1    = (const float*)d_in[6];   // [8,1024,4096]
  const float* rt_b1    = (const float*)d_in[7];   // [8,4096]
  const float* rt_w2    = (const float*)d_in[8];   // [8,4096,1024]
  const float* rt_b2    = (const float*)d_in[9];   // [8,1024]
  float* out = (float*)d_out;

  // ---- workspace layout ----
  char* p = (char*)d_ws;
  auto take = [&](size_t bytes) { char* q = p; p += (bytes + 255) & ~(size_t)255; return q; };
  u16*  Xb   = (u16*)take((size_t)NTOK * CDIM * 2);        //   8 MB
  u16*  W1t  = (u16*)take((size_t)HDIM * CDIM * 2);        //   8 MB  sh_w1^T [H][C]
  u16*  W2t  = (u16*)take((size_t)CDIM * HDIM * 2);        //   8 MB  sh_w2^T [C][H]
  u16*  RW1t = (u16*)take((size_t)NEXP * HDIM * CDIM * 2); //  64 MB  [E][H][C]
  u16*  RW2t = (u16*)take((size_t)NEXP * CDIM * HDIM * 2); //  64 MB  [E][C][H]
  u16*  Hu   = (u16*)take((size_t)SLOTS * HDIM * 2);       // 104 MB
  float* Yu  = (float*)take((size_t)SLOTS * CDIM * 4);     //  52 MB
  float* w01 = (float*)take((size_t)NTOK * 2 * 4);
  int*  e01  = (int*)take((size_t)NTOK * 2 * 4);
  int*  slot_of = (int*)take((size_t)NTOK * 2 * 4);
  int*  order   = (int*)take((size_t)SLOTS * 4);
  int*  tile_expert = (int*)take((size_t)NTILES * 4);
  float* pP  = (float*)take((size_t)RBLK * 8 * 4);         //  32 KB router prob partials
  int*  pC   = (int*)take((size_t)RBLK * 8 * 4);           //  32 KB router count partials
  int*  cursor = (int*)take(256);
  int*  roff   = (int*)take(256);
  size_t need = (size_t)(p - (char*)d_ws);
  if (ws_size < need) return;  // insufficient scratch -> fail visibly (poisoned out)

  // ---- pipeline ----
  init_kernel<<<52, 256, 0, stream>>>(order, tile_expert, cursor);
  xconv_kernel<<<(NTOK * CDIM / 4) / 256, 256, 0, stream>>>(X, Xb);
  tconv_kernel<<<dim3(HDIM / 32, CDIM / 32, 1), 256, 0, stream>>>(sh_w1, W1t, CDIM, HDIM);
  tconv_kernel<<<dim3(CDIM / 32, HDIM / 32, 1), 256, 0, stream>>>(sh_w2, W2t, HDIM, CDIM);
  tconv_kernel<<<dim3(HDIM / 32, CDIM / 32, NEXP), 256, 0, stream>>>(rt_w1, RW1t, CDIM, HDIM);
  tconv_kernel<<<dim3(CDIM / 32, HDIM / 32, NEXP), 256, 0, stream>>>(rt_w2, RW2t, HDIM, CDIM);
  router_kernel<<<RBLK, 256, 0, stream>>>(X, router_w, w01, e01, pP, pC);
  setup_kernel<<<1, 256, 0, stream>>>(pP, pC, roff, tile_expert, out + (size_t)NTOK * CDIM);
  scatter_kernel<<<NTOK / 256, 256, 0, stream>>>(e01, roff, cursor, order, slot_of);
  gemm_h_kernel<<<dim3(32, NTILES), 256, 0, stream>>>(
      Xb, W1t, RW1t, sh_b1, rt_b1, tile_expert, order, Hu);
  gemm_o_kernel<<<dim3(8, NTILES), 256, 0, stream>>>(
      Hu, W2t, RW2t, sh_b2, rt_b2, tile_expert, Yu);
  combine_kernel<<<(NTOK * CDIM / 4) / 256, 256, 0, stream>>>(Yu, w01, slot_of, out);
}

// Round 5
// 550.501 us; speedup vs baseline: 1.1872x; 1.1242x over previous
//
#include <hip/hip_runtime.h>

// MoE layer: B=4,T=1024,C=1024,H=4096,E=8, top-2 routing, shared expert.
// Sparse formulation: only top-2 experts per token are computed.
//
// R5: GEMMs moved to 256x256 tile, BK=64, 512 threads (8 waves 2Mx4N),
// 128KB LDS double-buffer, one barrier per K-step. 4x more MFMA per
// barrier-drain than the 128^2 tile (R4 was still drain-bound: MfmaUtil 16%,
// VALUBusy 15%, HBM 9%). Expert segments padded to 256. Conflict-free
// lane-major LDS chunks + XCD swizzle + setprio kept.

typedef unsigned short u16;
typedef __bf16 bf16x8 __attribute__((ext_vector_type(8)));
typedef float f32x4 __attribute__((ext_vector_type(4)));

#define NTOK 4096
#define CDIM 1024
#define HDIM 4096
#define NEXP 8
#define SLOTS 14336   // 4096 shared (16 tiles) + 10240 routed capacity (256-aligned segs)
#define NTILES 56     // SLOTS/256
#define RBLK 1024     // router grid (4 tokens/block)

static __device__ __forceinline__ u16 f2bf(float f) {   // round-to-nearest-even
  unsigned u = __float_as_uint(f);
  u += 0x7fffu + ((u >> 16) & 1u);
  return (u16)(u >> 16);
}

static __device__ __forceinline__ void gload16(const void* g, void* l) {
  __builtin_amdgcn_global_load_lds((const __attribute__((address_space(1))) unsigned int*)g,
                                   (__attribute__((address_space(3))) unsigned int*)l,
                                   16, 0, 0);
}

// ---------------- init: zero cursor, identity/pad slot map ----------------
__global__ void init_kernel(int* order, int* tile_expert, int* cursor) {
  int i = blockIdx.x * 256 + threadIdx.x;      // grid 56*256 = 14336
  if (i < SLOTS) order[i] = (i < NTOK) ? i : -1;
  if (i < NTILES) tile_expert[i] = (i < 16) ? 8 : -1;   // tiles 0..15 = shared expert
  if (i < NEXP) cursor[i] = 0;
}

// ---------------- X fp32 -> bf16 ----------------
__global__ void xconv_kernel(const float* __restrict__ X, u16* __restrict__ Xb) {
  int i = blockIdx.x * 256 + threadIdx.x;      // 4 elems each
  float4 v = ((const float4*)X)[i];
  u16 o0 = f2bf(v.x), o1 = f2bf(v.y), o2 = f2bf(v.z), o3 = f2bf(v.w);
  unsigned long long pack = (unsigned long long)o0 | ((unsigned long long)o1 << 16)
                          | ((unsigned long long)o2 << 32) | ((unsigned long long)o3 << 48);
  ((unsigned long long*)Xb)[i] = pack;
}

// ---------------- transpose + convert: src fp32 [b][R][Cc] -> dst bf16 [b][Cc][R] ----------------
__global__ void tconv_kernel(const float* __restrict__ src, u16* __restrict__ dst, int R, int Cc) {
  __shared__ float t[32][33];
  const size_t bofs = (size_t)blockIdx.z * R * Cc;
  src += bofs; dst += bofs;
  int tx = threadIdx.x & 31, ty = threadIdx.x >> 5;   // 32x8
  int r0 = blockIdx.y * 32, c0 = blockIdx.x * 32;
#pragma unroll
  for (int i = 0; i < 32; i += 8)
    t[ty + i][tx] = src[(size_t)(r0 + ty + i) * Cc + c0 + tx];
  __syncthreads();
#pragma unroll
  for (int i = 0; i < 32; i += 8)
    dst[(size_t)(c0 + ty + i) * R + r0 + tx] = f2bf(t[tx][ty + i]);
}

// ---------------- router: 1 wave/token, block-local reduction, NO global atomics ----------------
__global__ __launch_bounds__(256) void router_kernel(
    const float* __restrict__ X, const float* __restrict__ rw,
    float* __restrict__ w01, int* __restrict__ e01,
    float* __restrict__ pP, int* __restrict__ pC) {
  __shared__ float wP[4][8];
  __shared__ int wE[4][2];
  const int tid = threadIdx.x;
  const int w = tid >> 6, l = tid & 63;
  const int wid = blockIdx.x * 4 + w;   // token
  const float* x = X + (size_t)wid * CDIM;
  float s[8] = {0.f,0.f,0.f,0.f,0.f,0.f,0.f,0.f};
#pragma unroll 4
  for (int i = 0; i < 16; ++i) {
    int c = i * 64 + l;
    float xv = x[c];
    const float4* rp = (const float4*)(rw + c * 8);
    float4 r0 = rp[0], r1 = rp[1];
    s[0] += xv * r0.x; s[1] += xv * r0.y; s[2] += xv * r0.z; s[3] += xv * r0.w;
    s[4] += xv * r1.x; s[5] += xv * r1.y; s[6] += xv * r1.z; s[7] += xv * r1.w;
  }
#pragma unroll
  for (int off = 32; off; off >>= 1)
#pragma unroll
    for (int e = 0; e < 8; ++e) s[e] += __shfl_down(s[e], off);
  if (l == 0) {
    float m = s[0];
#pragma unroll
    for (int e = 1; e < 8; ++e) m = fmaxf(m, s[e]);
    float p[8], d = 0.f;
#pragma unroll
    for (int e = 0; e < 8; ++e) { p[e] = expf(s[e] - m); d += p[e]; }
    float inv = 1.f / d;
#pragma unroll
    for (int e = 0; e < 8; ++e) p[e] *= inv;
    int e0 = 0;
#pragma unroll
    for (int e = 1; e < 8; ++e) if (p[e] > p[e0]) e0 = e;   // ties -> lowest idx (jax)
    int e1 = -1;
#pragma unroll
    for (int e = 0; e < 8; ++e) if (e != e0 && (e1 < 0 || p[e] > p[e1])) e1 = e;
    w01[wid * 2] = p[e0]; w01[wid * 2 + 1] = p[e1];
    e01[wid * 2] = e0;    e01[wid * 2 + 1] = e1;
#pragma unroll
    for (int e = 0; e < 8; ++e) wP[w][e] = p[e];
    wE[w][0] = e0; wE[w][1] = e1;
  }
  __syncthreads();
  if (tid < 8) {
    pP[blockIdx.x * 8 + tid] = wP[0][tid] + wP[1][tid] + wP[2][tid] + wP[3][tid];
    int c = 0;
#pragma unroll
    for (int v = 0; v < 4; ++v) c += (wE[v][0] == tid) + (wE[v][1] == tid);
    pC[blockIdx.x * 8 + tid] = c;
  }
}

// ---------------- setup: reduce partials, offsets (256-aligned), tile map, aux ----------------
__global__ __launch_bounds__(256) void setup_kernel(
    const float* __restrict__ pP, const int* __restrict__ pC,
    int* __restrict__ roff, int* __restrict__ tile_expert, float* __restrict__ out_aux) {
  __shared__ float sP[32][8];
  __shared__ int   sC[32][8];
  const int tid = threadIdx.x;
  const int e = tid & 7, g = tid >> 3;   // 32 groups x 8 experts
  float fs = 0.f; int cs = 0;
  for (int b = g; b < RBLK; b += 32) { fs += pP[b * 8 + e]; cs += pC[b * 8 + e]; }
  sP[g][e] = fs; sC[g][e] = cs;
  __syncthreads();
  if (tid == 0) {
    float P[8]; int C[8];
    for (int e2 = 0; e2 < 8; ++e2) {
      float f2 = 0.f; int c2 = 0;
      for (int g2 = 0; g2 < 32; ++g2) { f2 += sP[g2][e2]; c2 += sC[g2][e2]; }
      P[e2] = f2; C[e2] = c2;
    }
    int off = NTOK;
    float a = 0.f;
    for (int e2 = 0; e2 < NEXP; ++e2) {
      roff[e2] = off;
      int nt = (C[e2] + 255) >> 8;
      int t0 = off >> 8;
      for (int i = 0; i < nt; ++i) tile_expert[t0 + i] = e2;
      off += nt << 8;
      a += (C[e2] * (1.f / NTOK)) * (P[e2] * (1.f / NTOK));
    }
    out_aux[0] = (float)NEXP * a;
  }
}

// ---------------- scatter: token -> slots, block-aggregated cursor ----------------
__global__ __launch_bounds__(256) void scatter_kernel(
    const int* __restrict__ e01, const int* __restrict__ roff,
    int* __restrict__ cursor, int* __restrict__ order, int* __restrict__ slot_of) {
  __shared__ int cnt_l[8];
  __shared__ int base_l[8];
  const int tid = threadIdx.x;
  const int t = blockIdx.x * 256 + tid;   // grid 16 blocks
  if (tid < 8) cnt_l[tid] = 0;
  __syncthreads();
  int e0 = e01[t * 2], e1 = e01[t * 2 + 1];
  int p0 = atomicAdd(&cnt_l[e0], 1);      // LDS atomics
  int p1 = atomicAdd(&cnt_l[e1], 1);
  __syncthreads();
  if (tid < 8) base_l[tid] = atomicAdd(&cursor[tid], cnt_l[tid]);  // 8 global atomics/block
  __syncthreads();
  int s0 = roff[e0] + base_l[e0] + p0;
  int s1 = roff[e1] + base_l[e1] + p1;
  order[s0] = t; order[s1] = t;
  slot_of[t * 2] = s0; slot_of[t * 2 + 1] = s1;
}

// LDS layout (both GEMMs): per 256x64 operand tile, 32 chunks of 1KB.
// Chunk c = g*2+kk (g = 16-row group 0..15, kk = 32-wide k-half); slot l holds
// (row = g*16 + (l&15), k = kk*32 + (l>>4)*8 .. +7). Wave w stages chunks
// 4w..4w+3 (rows 32w..32w+31). Every ds_read_b128 and gload16 dest is
// wave-uniform base + lane*16B -> zero bank conflicts (verified R3/R4).

// ---------------- GEMM1: hidden = relu(A @ W1^T + b1), A rows via order[], out bf16 ----------------
__global__ __launch_bounds__(512, 2) void gemm_h_kernel(
    const u16* __restrict__ Xb, const u16* __restrict__ W1t, const u16* __restrict__ RW1t,
    const float* __restrict__ sh_b1, const float* __restrict__ rt_b1,
    const int* __restrict__ tile_expert, const int* __restrict__ order,
    u16* __restrict__ Hu) {
  // bijective XCD swizzle: nwg = 16*52 = 832, q = 104 (n-fast decode)
  const int orig = blockIdx.y * 16 + blockIdx.x;
  const int wg = (orig & 7) * 104 + (orig >> 3);
  const int tile = wg >> 4, nidx = wg & 15;
  int e = tile_expert[tile];
  if (e < 0) return;
  const u16* Bw = (e == 8) ? W1t : RW1t + (size_t)e * HDIM * CDIM;
  const float* bias = (e == 8) ? sh_b1 : rt_b1 + e * HDIM;

  __shared__ u16 As[2 * 256 * 64];   // 64KB: [buf][32 chunks][512]
  __shared__ u16 Bs[2 * 256 * 64];   // 64KB

  const int tid = threadIdx.x;
  const int l = tid & 63, w = tid >> 6;     // 8 waves
  const int wm = w >> 2, wn = w & 3;        // 2M x 4N
  const int fr = l & 15, fq = l >> 4;
  const int m0 = tile * 256, n0 = nidx * 256;

  const int r0 = 32 * w + fr;        // staged rows (chunks 4w,4w+1)
  const int r1 = 32 * w + 16 + fr;   // (chunks 4w+2,4w+3)
  const int skoff = fq * 8;

  int tok0 = order[m0 + r0]; if (tok0 < 0) tok0 = 0;
  int tok1 = order[m0 + r1]; if (tok1 < 0) tok1 = 0;
  const u16* aSrc0 = Xb + (size_t)tok0 * CDIM + skoff;
  const u16* aSrc1 = Xb + (size_t)tok1 * CDIM + skoff;
  const u16* bSrc0 = Bw + (size_t)(n0 + r0) * CDIM + skoff;
  const u16* bSrc1 = Bw + (size_t)(n0 + r1) * CDIM + skoff;

  auto STAGE = [&](int bufofs, int kofs) {
    gload16(aSrc0 + kofs,      As + bufofs + (4 * w + 0) * 512);
    gload16(aSrc0 + kofs + 32, As + bufofs + (4 * w + 1) * 512);
    gload16(aSrc1 + kofs,      As + bufofs + (4 * w + 2) * 512);
    gload16(aSrc1 + kofs + 32, As + bufofs + (4 * w + 3) * 512);
    gload16(bSrc0 + kofs,      Bs + bufofs + (4 * w + 0) * 512);
    gload16(bSrc0 + kofs + 32, Bs + bufofs + (4 * w + 1) * 512);
    gload16(bSrc1 + kofs,      Bs + bufofs + (4 * w + 2) * 512);
    gload16(bSrc1 + kofs + 32, Bs + bufofs + (4 * w + 3) * 512);
  };

  f32x4 acc[8][4] = {};
  const int NT = CDIM / 64;   // 16
  STAGE(0, 0);
  __syncthreads();
  int cur = 0;
  for (int t = 0; t < NT; ++t) {
    if (t + 1 < NT) STAGE((cur ^ 1) * 16384, (t + 1) * 64);
    const u16* ab = As + cur * 16384 + l * 8;
    const u16* bb = Bs + cur * 16384 + l * 8;
    bf16x8 bv[4][2];
#pragma unroll
    for (int j = 0; j < 4; ++j) {
      bv[j][0] = *(const bf16x8*)&bb[((wn * 4 + j) * 2 + 0) * 512];
      bv[j][1] = *(const bf16x8*)&bb[((wn * 4 + j) * 2 + 1) * 512];
    }
    __builtin_amdgcn_s_setprio(1);
#pragma unroll
    for (int i = 0; i < 8; ++i) {
      bf16x8 a0 = *(const bf16x8*)&ab[((wm * 8 + i) * 2 + 0) * 512];
      bf16x8 a1 = *(const bf16x8*)&ab[((wm * 8 + i) * 2 + 1) * 512];
#pragma unroll
      for (int j = 0; j < 4; ++j) {
        acc[i][j] = __builtin_amdgcn_mfma_f32_16x16x32_bf16(a0, bv[j][0], acc[i][j], 0, 0, 0);
        acc[i][j] = __builtin_amdgcn_mfma_f32_16x16x32_bf16(a1, bv[j][1], acc[i][j], 0, 0, 0);
      }
    }
    __builtin_amdgcn_s_setprio(0);
    __syncthreads();
    cur ^= 1;
  }

  const size_t mb = m0 + wm * 128;
  const int nb = n0 + wn * 64;
#pragma unroll
  for (int j = 0; j < 4; ++j) {
    const int n_g = nb + j * 16 + fr;
    const float bvf = bias[n_g];
#pragma unroll
    for (int i = 0; i < 8; ++i)
#pragma unroll
      for (int r = 0; r < 4; ++r) {
        float v = acc[i][j][r] + bvf;
        v = fmaxf(v, 0.0f);
        Hu[(mb + i * 16 + fq * 4 + r) * (size_t)HDIM + n_g] = f2bf(v);
      }
  }
}

// ---------------- GEMM2: Yu = Hu @ W2^T + b2 (fp32 out) ----------------
__global__ __launch_bounds__(512, 2) void gemm_o_kernel(
    const u16* __restrict__ Hu, const u16* __restrict__ W2t, const u16* __restrict__ RW2t,
    const float* __restrict__ sh_b2, const float* __restrict__ rt_b2,
    const int* __restrict__ tile_expert,
    float* __restrict__ Yu) {
  // bijective XCD swizzle: nwg = 4*52 = 208, q = 26 (n-fast decode)
  const int orig = blockIdx.y * 4 + blockIdx.x;
  const int wg = (orig & 7) * 26 + (orig >> 3);
  const int tile = wg >> 2, nidx = wg & 3;
  int e = tile_expert[tile];
  if (e < 0) return;
  const u16* Bw = (e == 8) ? W2t : RW2t + (size_t)e * CDIM * HDIM;
  const float* bias = (e == 8) ? sh_b2 : rt_b2 + e * CDIM;

  __shared__ u16 As[2 * 256 * 64];
  __shared__ u16 Bs[2 * 256 * 64];

  const int tid = threadIdx.x;
  const int l = tid & 63, w = tid >> 6;
  const int wm = w >> 2, wn = w & 3;
  const int fr = l & 15, fq = l >> 4;
  const int m0 = tile * 256, n0 = nidx * 256;

  const int r0 = 32 * w + fr;
  const int r1 = 32 * w + 16 + fr;
  const int skoff = fq * 8;

  const u16* aSrc0 = Hu + (size_t)(m0 + r0) * HDIM + skoff;
  const u16* aSrc1 = Hu + (size_t)(m0 + r1) * HDIM + skoff;
  const u16* bSrc0 = Bw + (size_t)(n0 + r0) * HDIM + skoff;
  const u16* bSrc1 = Bw + (size_t)(n0 + r1) * HDIM + skoff;

  auto STAGE = [&](int bufofs, int kofs) {
    gload16(aSrc0 + kofs,      As + bufofs + (4 * w + 0) * 512);
    gload16(aSrc0 + kofs + 32, As + bufofs + (4 * w + 1) * 512);
    gload16(aSrc1 + kofs,      As + bufofs + (4 * w + 2) * 512);
    gload16(aSrc1 + kofs + 32, As + bufofs + (4 * w + 3) * 512);
    gload16(bSrc0 + kofs,      Bs + bufofs + (4 * w + 0) * 512);
    gload16(bSrc0 + kofs + 32, Bs + bufofs + (4 * w + 1) * 512);
    gload16(bSrc1 + kofs,      Bs + bufofs + (4 * w + 2) * 512);
    gload16(bSrc1 + kofs + 32, Bs + bufofs + (4 * w + 3) * 512);
  };

  f32x4 acc[8][4] = {};
  const int NT = HDIM / 64;   // 64
  STAGE(0, 0);
  __syncthreads();
  int cur = 0;
  for (int t = 0; t < NT; ++t) {
    if (t + 1 < NT) STAGE((cur ^ 1) * 16384, (t + 1) * 64);
    const u16* ab = As + cur * 16384 + l * 8;
    const u16* bb = Bs + cur * 16384 + l * 8;
    bf16x8 bv[4][2];
#pragma unroll
    for (int j = 0; j < 4; ++j) {
      bv[j][0] = *(const bf16x8*)&bb[((wn * 4 + j) * 2 + 0) * 512];
      bv[j][1] = *(const bf16x8*)&bb[((wn * 4 + j) * 2 + 1) * 512];
    }
    __builtin_amdgcn_s_setprio(1);
#pragma unroll
    for (int i = 0; i < 8; ++i) {
      bf16x8 a0 = *(const bf16x8*)&ab[((wm * 8 + i) * 2 + 0) * 512];
      bf16x8 a1 = *(const bf16x8*)&ab[((wm * 8 + i) * 2 + 1) * 512];
#pragma unroll
      for (int j = 0; j < 4; ++j) {
        acc[i][j] = __builtin_amdgcn_mfma_f32_16x16x32_bf16(a0, bv[j][0], acc[i][j], 0, 0, 0);
        acc[i][j] = __builtin_amdgcn_mfma_f32_16x16x32_bf16(a1, bv[j][1], acc[i][j], 0, 0, 0);
      }
    }
    __builtin_amdgcn_s_setprio(0);
    __syncthreads();
    cur ^= 1;
  }

  const size_t mb = m0 + wm * 128;
  const int nb = n0 + wn * 64;
#pragma unroll
  for (int j = 0; j < 4; ++j) {
    const int n_g = nb + j * 16 + fr;
    const float bvf = bias[n_g];
#pragma unroll
    for (int i = 0; i < 8; ++i)
#pragma unroll
      for (int r = 0; r < 4; ++r)
        Yu[(mb + i * 16 + fq * 4 + r) * (size_t)CDIM + n_g] = acc[i][j][r] + bvf;
  }
}

// ---------------- combine: out = shared + w0*expert0 + w1*expert1 ----------------
__global__ void combine_kernel(const float* __restrict__ Yu, const float* __restrict__ w01,
                               const int* __restrict__ slot_of, float* __restrict__ out) {
  int gid = blockIdx.x * 256 + threadIdx.x;   // 4096 blocks; 256 float4 per token row
  int t = gid >> 8;
  int c4 = gid & 255;
  int s0 = slot_of[t * 2], s1 = slot_of[t * 2 + 1];
  float wq0 = w01[t * 2], wq1 = w01[t * 2 + 1];
  float4 a  = ((const float4*)(Yu + (size_t)t  * CDIM))[c4];
  float4 b0 = ((const float4*)(Yu + (size_t)s0 * CDIM))[c4];
  float4 b1 = ((const float4*)(Yu + (size_t)s1 * CDIM))[c4];
  float4 rv;
  rv.x = a.x + wq0 * b0.x + wq1 * b1.x;
  rv.y = a.y + wq0 * b0.y + wq1 * b1.y;
  rv.z = a.z + wq0 * b0.z + wq1 * b1.z;
  rv.w = a.w + wq0 * b0.w + wq1 * b1.w;
  ((float4*)out)[gid] = rv;
}

extern "C" void kernel_launch(void* const* d_in, const int* in_sizes, int n_in,
                              void* d_out, int out_size, void* d_ws, size_t ws_size,
                              hipStream_t stream) {
  const float* X        = (const float*)d_in[0];   // [4096,1024]
  const float* router_w = (const float*)d_in[1];   // [1024,8]
  const float* sh_w1    = (const float*)d_in[2];   // [1024,4096]
  const float* sh_b1    = (const float*)d_in[3];   // [4096]
  const float* sh_w2    = (const float*)d_in[4];   // [4096,1024]
  const float* sh_b2    = (const float*)d_in[5];   // [1024]
  const float* rt_w1    = (const float*)d_in[6];   // [8,1024,4096]
  const float* rt_b1    = (const float*)d_in[7];   // [8,4096]
  const float* rt_w2    = (const float*)d_in[8];   // [8,4096,1024]
  const float* rt_b2    = (const float*)d_in[9];   // [8,1024]
  float* out = (float*)d_out;

  // ---- workspace layout ----
  char* p = (char*)d_ws;
  auto take = [&](size_t bytes) { char* q = p; p += (bytes + 255) & ~(size_t)255; return q; };
  u16*  Xb   = (u16*)take((size_t)NTOK * CDIM * 2);        //   8 MB
  u16*  W1t  = (u16*)take((size_t)HDIM * CDIM * 2);        //   8 MB  sh_w1^T [H][C]
  u16*  W2t  = (u16*)take((size_t)CDIM * HDIM * 2);        //   8 MB  sh_w2^T [C][H]
  u16*  RW1t = (u16*)take((size_t)NEXP * HDIM * CDIM * 2); //  64 MB  [E][H][C]
  u16*  RW2t = (u16*)take((size_t)NEXP * CDIM * HDIM * 2); //  64 MB  [E][C][H]
  u16*  Hu   = (u16*)take((size_t)SLOTS * HDIM * 2);       // 112 MB
  float* Yu  = (float*)take((size_t)SLOTS * CDIM * 4);     //  56 MB
  float* w01 = (float*)take((size_t)NTOK * 2 * 4);
  int*  e01  = (int*)take((size_t)NTOK * 2 * 4);
  int*  slot_of = (int*)take((size_t)NTOK * 2 * 4);
  int*  order   = (int*)take((size_t)SLOTS * 4);
  int*  tile_expert = (int*)take((size_t)NTILES * 4);
  float* pP  = (float*)take((size_t)RBLK * 8 * 4);         //  32 KB router prob partials
  int*  pC   = (int*)take((size_t)RBLK * 8 * 4);           //  32 KB router count partials
  int*  cursor = (int*)take(256);
  int*  roff   = (int*)take(256);
  size_t need = (size_t)(p - (char*)d_ws);
  if (ws_size < need) return;  // insufficient scratch -> fail visibly (poisoned out)

  // ---- pipeline ----
  init_kernel<<<NTILES, 256, 0, stream>>>(order, tile_expert, cursor);
  xconv_kernel<<<(NTOK * CDIM / 4) / 256, 256, 0, stream>>>(X, Xb);
  tconv_kernel<<<dim3(HDIM / 32, CDIM / 32, 1), 256, 0, stream>>>(sh_w1, W1t, CDIM, HDIM);
  tconv_kernel<<<dim3(CDIM / 32, HDIM / 32, 1), 256, 0, stream>>>(sh_w2, W2t, HDIM, CDIM);
  tconv_kernel<<<dim3(HDIM / 32, CDIM / 32, NEXP), 256, 0, stream>>>(rt_w1, RW1t, CDIM, HDIM);
  tconv_kernel<<<dim3(CDIM / 32, HDIM / 32, NEXP), 256, 0, stream>>>(rt_w2, RW2t, HDIM, CDIM);
  router_kernel<<<RBLK, 256, 0, stream>>>(X, router_w, w01, e01, pP, pC);
  setup_kernel<<<1, 256, 0, stream>>>(pP, pC, roff, tile_expert, out + (size_t)NTOK * CDIM);
  scatter_kernel<<<NTOK / 256, 256, 0, stream>>>(e01, roff, cursor, order, slot_of);
  gemm_h_kernel<<<dim3(16, 52), 512, 0, stream>>>(
      Xb, W1t, RW1t, sh_b1, rt_b1, tile_expert, order, Hu);
  gemm_o_kernel<<<dim3(4, 52), 512, 0, stream>>>(
      Hu, W2t, RW2t, sh_b2, rt_b2, tile_expert, Yu);
  combine_kernel<<<(NTOK * CDIM / 4) / 256, 256, 0, stream>>>(Yu, w01, slot_of, out);
}